// Round 16
// baseline (84.009 us; speedup 1.0000x reference)
//
#include <hip/hip_runtime.h>

typedef __bf16 bf16x8 __attribute__((ext_vector_type(8)));
typedef float floatx4 __attribute__((ext_vector_type(4)));

__device__ __forceinline__ ushort f2bf(float f) {
  union { float f; unsigned u; } a; a.f = f;
  unsigned u = a.u;
  unsigned r = (u + 0x7FFFu + ((u >> 16) & 1u)) >> 16;
  return (ushort)r;
}
__device__ __forceinline__ float bf2f(ushort u) {
  union { unsigned u; float f; } a; a.u = ((unsigned)u) << 16;
  return a.f;
}

// async global->LDS, 16B per lane; lds base must be wave-uniform
__device__ __forceinline__ void gl_lds16(const ushort* g, ushort* l) {
  __builtin_amdgcn_global_load_lds((const __attribute__((address_space(1))) void*)g,
                                   (__attribute__((address_space(3))) void*)l, 16, 0, 0);
}

// within-chunk prefix product (sequential scan, 64 lanes)
__device__ __forceinline__ float chunk_scan(float g) {
  int lane = threadIdx.x & 63;
  #pragma unroll
  for (int m = 1; m < 64; m <<= 1) {
    float o = __shfl_up(g, m);
    if (lane >= m) g *= o;
  }
  return g;
}

// swizzled index helpers
#define SWZH(row, col, stride) ((((row) * (stride)) + (col)) ^ (((row) & 7) << 3))       // ushort tiles
#define SWZC(row, col) ((((row) * 128) + (col)) ^ ((((row) >> 3) & 7) << 2))             // f32 C-tile

// LESSONS LOG:
// R7/R8: grid-barrier fusion of scan phases = +110us. Keep separate kernels.
// R11:   8-wave 64x128 GEMM = +6us vs 4-wave 2x4-acc.
// R13:   BK=128 = +16us (16-way LDS bank conflicts at 256B row stride).
// R15:   depth-1 dbuf pipeline (stage-next-before-compute) = -3.3us. KEEP.
// R16:   T1 XCD swizzle on GEMMs: contiguous block chunks per XCD -> B-panels
//        L2-resident -> lower stage latency in this latency-bound regime.

// ---------------- fused: weight conversions (blocks 0..4095) + gate (4096..6143) ----------------
__global__ __launch_bounds__(256) void prep_all_kernel(
    const float* __restrict__ x,
    const float* __restrict__ Wq, const float* __restrict__ Wk,
    const float* __restrict__ Wv, const float* __restrict__ Wgp,
    const float* __restrict__ Wout,
    const float* __restrict__ Wg1, const float* __restrict__ Wg2,
    ushort* __restrict__ WcatT, ushort* __restrict__ WoutT,
    float* __restrict__ gamma, ushort* __restrict__ xb) {
  __shared__ __align__(16) float smem[1344];
  int bid = blockIdx.x;
  int tid = threadIdx.x;

  if (bid < 4096) {
    int nv = (bid & 127) * 32, k0 = (bid >> 7) * 32;
    const float* W; ushort* dst; int N, ncol, nrow; float scale = 1.f;
    if (nv < 512)       { W = Wq;   N = 512;  ncol = nv;         nrow = nv;        dst = WcatT; }
    else if (nv < 1024) { W = Wk;   N = 512;  ncol = nv - 512;   nrow = nv;        dst = WcatT; scale = 0.125f; }
    else if (nv < 2048) { W = Wv;   N = 1024; ncol = nv - 1024;  nrow = nv;        dst = WcatT; }
    else if (nv < 3072) { W = Wgp;  N = 1024; ncol = nv - 2048;  nrow = nv;        dst = WcatT; }
    else                { W = Wout; N = 1024; ncol = nv - 3072;  nrow = nv - 3072; dst = WoutT; }
    float* tile = smem;  // [32][33]
    int xi = tid & 31, yi = tid >> 5;
    #pragma unroll
    for (int i = 0; i < 32; i += 8)
      tile[(yi + i) * 33 + xi] = W[(size_t)(k0 + yi + i) * N + ncol + xi];
    __syncthreads();
    #pragma unroll
    for (int i = 0; i < 32; i += 8)
      dst[(size_t)(nrow + yi + i) * 1024 + k0 + xi] = f2bf(tile[xi * 33 + yi + i] * scale);
    return;
  }

  int rowi = bid - 4096;          // b*1024 + l
  int b = rowi >> 10, l = rowi & 1023;
  float* xrow = smem;             // 1024
  float* part = smem + 1024;      // [16][17]
  float* tsh  = smem + 1296;      // 16

  {
    float4 v = *(const float4*)(x + (size_t)rowi * 1024 + tid * 4);
    ushort4 o;
    o.x = f2bf(v.x); o.y = f2bf(v.y); o.z = f2bf(v.z); o.w = f2bf(v.w);
    *(ushort4*)(xb + (size_t)rowi * 1024 + tid * 4) = o;
    *(float4*)&xrow[tid * 4] = v;
  }
  __syncthreads();

  {
    int j = tid & 15, slice = tid >> 4;
    const float* xr = xrow + slice * 64;
    float p = 0.f;
    #pragma unroll 4
    for (int kk = 0; kk < 64; kk++)
      p += xr[kk] * Wg1[(size_t)(slice * 64 + kk) * 16 + j];
    part[slice * 17 + j] = p;
  }
  __syncthreads();
  if (tid < 16) {
    float s = 0.f;
    #pragma unroll
    for (int i = 0; i < 16; i++) s += part[i * 17 + tid];
    tsh[tid] = s;
  }
  __syncthreads();

  float ls0, ls1;
  {
    int n = tid;
    float kg = 0.f;
    #pragma unroll
    for (int j = 0; j < 16; j++) kg += tsh[j] * Wg2[j * 512 + n];
    ls0 = (kg >= 0.f) ? -log1pf(expf(-kg)) : (kg - log1pf(expf(kg)));
  }
  {
    int n = tid + 256;
    float kg = 0.f;
    #pragma unroll
    for (int j = 0; j < 16; j++) kg += tsh[j] * Wg2[j * 512 + n];
    ls1 = (kg >= 0.f) ? -log1pf(expf(-kg)) : (kg - log1pf(expf(kg)));
  }
  #pragma unroll
  for (int m = 32; m >= 1; m >>= 1) {
    ls0 += __shfl_xor(ls0, m);
    ls1 += __shfl_xor(ls1, m);
  }
  if ((tid & 63) == 0) {
    int w = tid >> 6;
    gamma[(size_t)(b * 8 + w) * 1024 + l]       = expf(ls0 * (1.f / 1024.f)) + 1e-6f;
    gamma[(size_t)(b * 8 + w + 4) * 1024 + l]   = expf(ls1 * (1.f / 1024.f)) + 1e-6f;
  }
}

// ---------------- projection GEMM, 64x128 tile, 4 waves, BK=64, dbuf pipeline, XCD swizzle ----------------
__global__ __launch_bounds__(256) void gemm_proj_kernel(
    const ushort* __restrict__ A, const ushort* __restrict__ BT,
    const float* __restrict__ gamma, const float* __restrict__ bgp,
    ushort* __restrict__ Qb, ushort* __restrict__ Kb,
    ushort* __restrict__ Ktb, ushort* __restrict__ Vtb,
    ushort* __restrict__ gsilu) {
  const int K = 1024;
  // 2 x (A 8KB + B 16KB) staging dbuf = 48KB; epilogue Cs (32KB) overlays [0,32KB)
  __shared__ __align__(16) char ldsraw[49152];
  float* Cs = (float*)ldsraw;
  __shared__ float ssh[2][64];
  __shared__ float bsh[128];

  int tid = threadIdx.x;
  int lane = tid & 63, wid = tid >> 6;
  int wr = wid >> 1, wc = wid & 1;

  // T1 XCD swizzle: 768 blocks, 96 contiguous per XCD (768 % 8 == 0 -> bijective)
  int fid = blockIdx.y * 32 + blockIdx.x;
  int nid = (fid & 7) * 96 + (fid >> 3);
  int bxs = nid & 31, bys = nid >> 5;

  int m0 = bxs * 64, n0 = bys * 128;
  int by = bys;
  int rtype = (by < 4) ? 0 : (by < 8) ? 1 : (by < 16) ? 2 : 3;  // Q,K,V,G
  int b = m0 >> 10, lbase = m0 & 1023;

  // inline prefix-product: waves 0,1 handle the 2 heads
  if (rtype <= 1 && wid < 2) {
    int h = ((n0 - (rtype << 9)) >> 6) + wid;
    int bh = b * 8 + h;
    float a = chunk_scan(gamma[(size_t)bh * 1024 + lbase + lane]);
    float Ac = __shfl(a, 63);
    ssh[wid][lane] = (rtype == 0) ? a : (Ac / a);
  } else if (rtype == 3) {
    if (tid < 128) bsh[tid] = bgp[n0 - 2048 + tid];
  }

  floatx4 acc[2][4];
  #pragma unroll
  for (int r = 0; r < 2; r++)
    #pragma unroll
    for (int c = 0; c < 4; c++)
      acc[r][c] = (floatx4){0.f, 0.f, 0.f, 0.f};

  int srA = wid * 16 + (lane >> 3);
  int srB = wid * 32 + (lane >> 3);
  int sc = (lane & 7) * 8;
  const ushort* ag = A + (size_t)(m0 + srA) * K + sc;
  const ushort* bg = BT + (size_t)(n0 + srB) * K + sc;
  int aoff = (wid * 16) * 64;   // element offset within A region (wave-uniform)
  int boff = (wid * 32) * 64;
  int row = lane & 15, kseg = (lane >> 4) << 3;

  // prologue: stage k0=0 into buffer 0
  {
    ushort* asb = (ushort*)ldsraw + aoff;
    ushort* bsb = (ushort*)(ldsraw + 8192) + boff;
    #pragma unroll
    for (int i = 0; i < 2; i++)
      gl_lds16(ag + (size_t)(i * 8) * K, asb + i * 8 * 64);
    #pragma unroll
    for (int i = 0; i < 4; i++)
      gl_lds16(bg + (size_t)(i * 8) * K, bsb + i * 8 * 64);
  }
  __syncthreads();   // buffer 0 ready

  for (int t = 0; t < 16; t++) {
    int p = t & 1;
    if (t < 15) {    // issue next-tile stage BEFORE compute — latency hides under MFMA
      char* nb = ldsraw + (p ^ 1) * 24576;
      ushort* asb = (ushort*)nb + aoff;
      ushort* bsb = (ushort*)(nb + 8192) + boff;
      int k0 = (t + 1) * 64;
      #pragma unroll
      for (int i = 0; i < 2; i++)
        gl_lds16(ag + (size_t)(i * 8) * K + k0, asb + i * 8 * 64);
      #pragma unroll
      for (int i = 0; i < 4; i++)
        gl_lds16(bg + (size_t)(i * 8) * K + k0, bsb + i * 8 * 64);
    }
    const ushort* As_ = (const ushort*)(ldsraw + p * 24576);
    const ushort* Bs_ = (const ushort*)(ldsraw + p * 24576 + 8192);
    #pragma unroll
    for (int kk = 0; kk < 64; kk += 32) {
      bf16x8 av[2], bv[4];
      #pragma unroll
      for (int r = 0; r < 2; r++)
        av[r] = *(const bf16x8*)&As_[(wr * 32 + r * 16 + row) * 64 + kk + kseg];
      #pragma unroll
      for (int c = 0; c < 4; c++)
        bv[c] = *(const bf16x8*)&Bs_[(wc * 64 + c * 16 + row) * 64 + kk + kseg];
      #pragma unroll
      for (int r = 0; r < 2; r++)
        #pragma unroll
        for (int c = 0; c < 4; c++)
          acc[r][c] = __builtin_amdgcn_mfma_f32_16x16x32_bf16(av[r], bv[c], acc[r][c], 0, 0, 0);
    }
    __syncthreads();  // drains this iteration's stage (hidden under compute) + WAR barrier
  }

  // epilogue: acc -> swizzled f32 LDS tile
  #pragma unroll
  for (int r = 0; r < 2; r++) {
    int crow = wr * 32 + r * 16 + ((lane >> 4) << 2);
    #pragma unroll
    for (int c = 0; c < 4; c++) {
      int ccol = wc * 64 + c * 16 + (lane & 15);
      #pragma unroll
      for (int i = 0; i < 4; i++)
        Cs[SWZC(crow + i, ccol)] = acc[r][c][i];
    }
  }
  __syncthreads();

  if (rtype == 0) {
    #pragma unroll
    for (int it = 0; it < 4; it++) {
      int u = tid + it * 256;
      int rw = u >> 4, col8 = (u & 15) * 8;
      int hh = col8 >> 6, d = col8 & 63;
      float a = ssh[hh][rw];
      float4 v0 = *(const float4*)&Cs[SWZC(rw, col8)];
      float4 v1 = *(const float4*)&Cs[SWZC(rw, col8 + 4)];
      ushort o[8];
      o[0]=f2bf(v0.x*a); o[1]=f2bf(v0.y*a); o[2]=f2bf(v0.z*a); o[3]=f2bf(v0.w*a);
      o[4]=f2bf(v1.x*a); o[5]=f2bf(v1.y*a); o[6]=f2bf(v1.z*a); o[7]=f2bf(v1.w*a);
      int bh = b * 8 + (n0 >> 6) + hh;
      *(uint4*)(Qb + ((size_t)bh * 1024 + lbase + rw) * 64 + d) = *(uint4*)&o[0];
    }
  } else if (rtype == 1) {
    #pragma unroll
    for (int it = 0; it < 4; it++) {
      int u = tid + it * 256;
      int rw = u >> 4, col8 = (u & 15) * 8;
      int hh = col8 >> 6, d = col8 & 63;
      float4 v0 = *(const float4*)&Cs[SWZC(rw, col8)];
      float4 v1 = *(const float4*)&Cs[SWZC(rw, col8 + 4)];
      ushort o[8];
      o[0]=f2bf(v0.x); o[1]=f2bf(v0.y); o[2]=f2bf(v0.z); o[3]=f2bf(v0.w);
      o[4]=f2bf(v1.x); o[5]=f2bf(v1.y); o[6]=f2bf(v1.z); o[7]=f2bf(v1.w);
      int bh = b * 8 + ((n0 - 512) >> 6) + hh;
      *(uint4*)(Kb + ((size_t)bh * 1024 + lbase + rw) * 64 + d) = *(uint4*)&o[0];
    }
    #pragma unroll
    for (int it = 0; it < 4; it++) {
      int u = tid + it * 256;
      int l0 = (u & 7) * 8, dd = (u >> 3) & 63, hh = u >> 9;
      ushort o[8];
      #pragma unroll
      for (int j = 0; j < 8; j++)
        o[j] = f2bf(Cs[SWZC(l0 + j, hh * 64 + dd)] * ssh[hh][l0 + j]);
      int bh = b * 8 + ((n0 - 512) >> 6) + hh;
      *(uint4*)(Ktb + ((size_t)(bh * 64 + dd)) * 1024 + lbase + l0) = *(uint4*)&o[0];
    }
  } else if (rtype == 2) {
    #pragma unroll
    for (int it = 0; it < 4; it++) {
      int u = tid + it * 256;
      int l0 = (u & 7) * 8, e = u >> 3;
      ushort o[8];
      #pragma unroll
      for (int j = 0; j < 8; j++)
        o[j] = f2bf(Cs[SWZC(l0 + j, e)]);
      int bh = b * 8 + ((n0 - 1024) >> 7);
      *(uint4*)(Vtb + ((size_t)(bh * 128 + e)) * 1024 + lbase + l0) = *(uint4*)&o[0];
    }
  } else {
    #pragma unroll
    for (int it = 0; it < 4; it++) {
      int u = tid + it * 256;
      int rw = u >> 4, col8 = (u & 15) * 8;
      float4 v0 = *(const float4*)&Cs[SWZC(rw, col8)];
      float4 v1 = *(const float4*)&Cs[SWZC(rw, col8 + 4)];
      float vv[8] = {v0.x, v0.y, v0.z, v0.w, v1.x, v1.y, v1.z, v1.w};
      ushort o[8];
      #pragma unroll
      for (int j = 0; j < 8; j++) {
        float z = vv[j] + bsh[col8 + j];
        o[j] = f2bf(z / (1.f + expf(-z)));
      }
      *(uint4*)(gsilu + (size_t)(m0 + rw) * 1024 + (n0 - 2048) + col8) = *(uint4*)&o[0];
    }
  }
}

// ---------------- per-chunk Tt[e][d] = sum_s V[s][e] * w_s k[s][d]  (MFMA, 8 waves) ----------------
__global__ __launch_bounds__(512) void chunk_T_kernel(const ushort* __restrict__ Ktb,
                                                      const ushort* __restrict__ Vtb,
                                                      float* __restrict__ Tt) {
  int c = blockIdx.x, bh = blockIdx.y;
  int tid = threadIdx.x;
  int lane = tid & 63, wid = tid >> 6;      // 0..7
  int wq = wid & 3, eh = wid >> 2;
  int col_l = lane & 15, kseg8 = (lane >> 4) * 8;
  int d0w = wq * 16;

  __shared__ __align__(16) ushort Kt[64 * 64];
  __shared__ __align__(16) ushort Vs[128 * 64];

  {
    int row = tid >> 3, col8 = tid & 7;
    *(uint4*)&Kt[SWZH(row, col8 * 8, 64)] =
        *(const uint4*)(Ktb + ((size_t)(bh * 64 + row)) * 1024 + c * 64 + col8 * 8);
  }
  #pragma unroll
  for (int i = 0; i < 2; i++) {
    int u = tid + i * 512;
    int row = u >> 3, col8 = u & 7;
    *(uint4*)&Vs[SWZH(row, col8 * 8, 64)] =
        *(const uint4*)(Vtb + ((size_t)(bh * 128 + row)) * 1024 + c * 64 + col8 * 8);
  }
  __syncthreads();

  floatx4 acc[4];
  #pragma unroll
  for (int i = 0; i < 4; i++) acc[i] = (floatx4){0.f, 0.f, 0.f, 0.f};

  #pragma unroll
  for (int kk = 0; kk < 64; kk += 32) {
    bf16x8 kb = *(const bf16x8*)&Kt[SWZH(d0w + col_l, kk + kseg8, 64)];
    #pragma unroll
    for (int j = 0; j < 4; j++) {
      bf16x8 vb = *(const bf16x8*)&Vs[SWZH((eh * 4 + j) * 16 + col_l, kk + kseg8, 64)];
      acc[j] = __builtin_amdgcn_mfma_f32_16x16x32_bf16(vb, kb, acc[j], 0, 0, 0);
    }
  }

  float* To = Tt + (size_t)(bh * 16 + c) * 8192;
  #pragma unroll
  for (int j = 0; j < 4; j++) {
    #pragma unroll
    for (int r = 0; r < 4; r++) {
      int e = (eh * 4 + j) * 16 + (lane >> 4) * 4 + r;
      To[(size_t)e * 64 + d0w + col_l] = acc[j][r];
    }
  }
}

// ---------------- inter-chunk state recurrence (e-sliced, inline Atot, prefetched) ----------------
__global__ __launch_bounds__(256) void state_kernel(const float* __restrict__ Tt,
                                                    const float* __restrict__ gamma,
                                                    ushort* __restrict__ Stb) {
  int es = blockIdx.x, bh = blockIdx.y;
  int tid = threadIdx.x;
  int lane = tid & 63, wid = tid >> 6;
  __shared__ float Atot_sh[16];

  #pragma unroll
  for (int j = 0; j < 4; j++) {
    int cc = wid * 4 + j;
    float a = chunk_scan(gamma[(size_t)bh * 1024 + cc * 64 + lane]);
    if (lane == 63) Atot_sh[cc] = a;
  }
  __syncthreads();

  size_t off = (size_t)es * 512 + tid * 2;
  float2 t[16];
  #pragma unroll
  for (int c = 0; c < 16; c++)
    t[c] = *(const float2*)(Tt + (size_t)(bh * 16 + c) * 8192 + off);
  float2 S = {0.f, 0.f};
  #pragma unroll
  for (int c = 0; c < 16; c++) {
    ushort2 o; o.x = f2bf(S.x); o.y = f2bf(S.y);
    *(ushort2*)(Stb + (size_t)(bh * 16 + c) * 8192 + off) = o;
    float A = Atot_sh[c];
    S.x = A * S.x + t[c].x;
    S.y = A * S.y + t[c].y;
  }
}

// ---------------- per-chunk output (MFMA, 8 waves) + LN + gate mult -> bf16 ----------------
__global__ __launch_bounds__(512) void out_chunk_kernel(const float* __restrict__ gamma,
                                                        const ushort* __restrict__ Qb,
                                                        const ushort* __restrict__ Kb,
                                                        const ushort* __restrict__ Stb,
                                                        const ushort* __restrict__ Vtb,
                                                        const ushort* __restrict__ gsilu,
                                                        ushort* __restrict__ gout) {
  int c = blockIdx.x, bh = blockIdx.y;
  int b = bh >> 3, h = bh & 7;
  int tid = threadIdx.x;
  int lane = tid & 63, wid = tid >> 6;      // 0..7
  int wq = wid & 3, eh = wid >> 2;
  int col_l = lane & 15, kseg8 = (lane >> 4) * 8;
  int t0w = wq * 16;

  __shared__ __align__(16) ushort Qs[64 * 64];
  __shared__ __align__(16) ushort Ks[64 * 64];
  __shared__ __align__(16) ushort Ss[128 * 64];
  __shared__ __align__(16) ushort Vs[128 * 64];
  __shared__ __align__(16) ushort Ps[64 * 64];
  __shared__ __align__(16) ushort Gz[64 * 128];
  __shared__ float inva_sh[64];
  __shared__ float2 red[2][4][16];

  // inline 1/prefix
  if (wid == 0) {
    float a = chunk_scan(gamma[(size_t)bh * 1024 + c * 64 + lane]);
    inva_sh[lane] = 1.f / a;
  }

  {
    int row = tid >> 3, col8 = tid & 7;
    *(uint4*)&Qs[SWZH(row, col8 * 8, 64)] =
        *(const uint4*)(Qb + ((size_t)(bh * 1024 + c * 64 + row)) * 64 + col8 * 8);
    *(uint4*)&Ks[SWZH(row, col8 * 8, 64)] =
        *(const uint4*)(Kb + ((size_t)(bh * 1024 + c * 64 + row)) * 64 + col8 * 8);
  }
  #pragma unroll
  for (int i = 0; i < 2; i++) {
    int u = tid + i * 512;
    int row = u >> 3, col8 = u & 7;
    *(uint4*)&Ss[SWZH(row, col8 * 8, 64)] =
        *(const uint4*)(Stb + (size_t)(bh * 16 + c) * 8192 + (size_t)row * 64 + col8 * 8);
    *(uint4*)&Vs[SWZH(row, col8 * 8, 64)] =
        *(const uint4*)(Vtb + ((size_t)(bh * 128 + row)) * 1024 + c * 64 + col8 * 8);
  }
  #pragma unroll
  for (int i = 0; i < 2; i++) {
    int u = tid + i * 512;
    int row = u >> 4, ch = u & 15;
    *(uint4*)&Gz[SWZH(row, ch * 8, 128)] =
        *(const uint4*)(gsilu + ((size_t)(b * 1024 + c * 64 + row)) * 1024 + h * 128 + ch * 8);
  }
  __syncthreads();

  floatx4 pacc[2];
  floatx4 acc[4];
  #pragma unroll
  for (int i = 0; i < 2; i++) pacc[i] = (floatx4){0.f, 0.f, 0.f, 0.f};
  #pragma unroll
  for (int i = 0; i < 4; i++) acc[i] = (floatx4){0.f, 0.f, 0.f, 0.f};

  #pragma unroll
  for (int kk = 0; kk < 64; kk += 32) {
    bf16x8 qb = *(const bf16x8*)&Qs[SWZH(t0w + col_l, kk + kseg8, 64)];
    #pragma unroll
    for (int j = 0; j < 2; j++) {
      int fs = eh * 2 + j;
      bf16x8 kb = *(const bf16x8*)&Ks[SWZH(fs * 16 + col_l, kk + kseg8, 64)];
      pacc[j] = __builtin_amdgcn_mfma_f32_16x16x32_bf16(kb, qb, pacc[j], 0, 0, 0);
    }
    #pragma unroll
    for (int j = 0; j < 4; j++) {
      int fe = eh * 4 + j;
      bf16x8 sb = *(const bf16x8*)&Ss[SWZH(fe * 16 + col_l, kk + kseg8, 64)];
      acc[j] = __builtin_amdgcn_mfma_f32_16x16x32_bf16(sb, qb, acc[j], 0, 0, 0);
    }
  }

  int tl = t0w + col_l;
  #pragma unroll
  for (int j = 0; j < 2; j++) {
    int fs = eh * 2 + j;
    ushort o[4];
    #pragma unroll
    for (int r = 0; r < 4; r++) {
      int s = fs * 16 + (lane >> 4) * 4 + r;
      float pv = (s <= tl) ? pacc[j][r] * inva_sh[s] : 0.f;
      o[r] = f2bf(pv);
    }
    int s0 = fs * 16 + (lane >> 4) * 4;
    *(ushort4*)&Ps[SWZH(tl, s0, 64)] = *(ushort4*)&o[0];
  }
  __syncthreads();

  #pragma unroll
  for (int kk = 0; kk < 64; kk += 32) {
    bf16x8 pb = *(const bf16x8*)&Ps[SWZH(t0w + col_l, kk + kseg8, 64)];
    #pragma unroll
    for (int j = 0; j < 4; j++) {
      int fe = eh * 4 + j;
      bf16x8 vb = *(const bf16x8*)&Vs[SWZH(fe * 16 + col_l, kk + kseg8, 64)];
      acc[j] = __builtin_amdgcn_mfma_f32_16x16x32_bf16(vb, pb, acc[j], 0, 0, 0);
    }
  }
  __syncthreads();

  float s1 = 0.f, s2 = 0.f;
  #pragma unroll
  for (int j = 0; j < 4; j++)
    #pragma unroll
    for (int r = 0; r < 4; r++) {
      float v = acc[j][r];
      s1 += v; s2 += v * v;
    }
  s1 += __shfl_xor(s1, 16); s2 += __shfl_xor(s2, 16);
  s1 += __shfl_xor(s1, 32); s2 += __shfl_xor(s2, 32);
  if (lane < 16) red[eh][wq][lane] = make_float2(s1, s2);
  __syncthreads();
  float2 oth = red[1 - eh][wq][col_l];
  float S1 = s1 + oth.x, S2 = s2 + oth.y;
  float mu = S1 * (1.f / 128.f);
  float var = S2 * (1.f / 128.f) - mu * mu;
  float rs = rsqrtf(var + 1e-5f);

  ushort* Gs = Vs;  // reuse (Vs reads done, synced above)
  #pragma unroll
  for (int j = 0; j < 4; j++)
    #pragma unroll
    for (int r = 0; r < 4; r++) {
      int e = (eh * 4 + j) * 16 + (lane >> 4) * 4 + r;
      float y = (acc[j][r] - mu) * rs;
      float g = bf2f(Gz[SWZH(tl, e, 128)]);
      Gs[SWZH(tl, e, 128)] = f2bf(y * g);
    }
  __syncthreads();

  #pragma unroll
  for (int i = 0; i < 2; i++) {
    int u = tid + i * 512;
    int row = u >> 4, ch = u & 15;
    *(uint4*)(gout + ((size_t)(b * 1024 + c * 64 + row)) * 1024 + h * 128 + ch * 8) =
        *(uint4*)&Gs[SWZH(row, ch * 8, 128)];
  }
}

// ---------------- output GEMM: 64x128 tile, 4 waves, BK=64, dbuf pipeline, XCD swizzle ----------------
__global__ __launch_bounds__(256) void gemm_out_kernel(const ushort* __restrict__ A,
                                                       const ushort* __restrict__ BT,
                                                       float* __restrict__ C) {
  const int K = 1024, N = 1024;
  __shared__ __align__(16) char ldsraw[49152];   // 2 x (A 8KB + B 16KB)
  int tid = threadIdx.x;
  int lane = tid & 63, wid = tid >> 6;
  int wr = wid >> 1, wc = wid & 1;

  // T1 XCD swizzle: 256 blocks, 32 contiguous per XCD -> each XCD owns one n-panel
  int fid = blockIdx.y * 32 + blockIdx.x;
  int nid = (fid & 7) * 32 + (fid >> 3);
  int m0 = (nid & 31) * 64, n0 = (nid >> 5) * 128;

  int row = lane & 15, kseg = (lane >> 4) << 3;

  floatx4 acc[2][4];
  #pragma unroll
  for (int r = 0; r < 2; r++)
    #pragma unroll
    for (int c = 0; c < 4; c++)
      acc[r][c] = (floatx4){0.f, 0.f, 0.f, 0.f};

  int srowA = wid * 16 + (lane >> 3);
  int srowB = wid * 32 + (lane >> 3);
  int scol = (lane & 7) * 8;
  const ushort* ag = A + (size_t)(m0 + srowA) * K + scol;
  const ushort* bg = BT + (size_t)(n0 + srowB) * K + scol;
  int aoff = (wid * 16) * 64;
  int boff = (wid * 32) * 64;

  {
    ushort* asb = (ushort*)ldsraw + aoff;
    ushort* bsb = (ushort*)(ldsraw + 8192) + boff;
    #pragma unroll
    for (int i = 0; i < 2; i++)
      gl_lds16(ag + (size_t)(i * 8) * K, asb + i * 8 * 64);
    #pragma unroll
    for (int i = 0; i < 4; i++)
      gl_lds16(bg + (size_t)(i * 8) * K, bsb + i * 8 * 64);
  }
  __syncthreads();

  for (int t = 0; t < 16; t++) {
    int p = t & 1;
    if (t < 15) {
      char* nb = ldsraw + (p ^ 1) * 24576;
      ushort* asb = (ushort*)nb + aoff;
      ushort* bsb = (ushort*)(nb + 8192) + boff;
      int k0 = (t + 1) * 64;
      #pragma unroll
      for (int i = 0; i < 2; i++)
        gl_lds16(ag + (size_t)(i * 8) * K + k0, asb + i * 8 * 64);
      #pragma unroll
      for (int i = 0; i < 4; i++)
        gl_lds16(bg + (size_t)(i * 8) * K + k0, bsb + i * 8 * 64);
    }
    const ushort* As_ = (const ushort*)(ldsraw + p * 24576);
    const ushort* Bs_ = (const ushort*)(ldsraw + p * 24576 + 8192);
    #pragma unroll
    for (int kk = 0; kk < 64; kk += 32) {
      bf16x8 av[2], bv[4];
      #pragma unroll
      for (int r = 0; r < 2; r++)
        av[r] = *(const bf16x8*)&As_[(wr * 32 + r * 16 + row) * 64 + kk + kseg];
      #pragma unroll
      for (int c = 0; c < 4; c++)
        bv[c] = *(const bf16x8*)&Bs_[(wc * 64 + c * 16 + row) * 64 + kk + kseg];
      #pragma unroll
      for (int r = 0; r < 2; r++)
        #pragma unroll
        for (int c = 0; c < 4; c++)
          acc[r][c] = __builtin_amdgcn_mfma_f32_16x16x32_bf16(av[r], bv[c], acc[r][c], 0, 0, 0);
    }
    __syncthreads();
  }

  int r4 = (lane >> 4) << 2;
  #pragma unroll
  for (int r = 0; r < 2; r++)
    #pragma unroll
    for (int c = 0; c < 4; c++) {
      int crow = m0 + wr * 32 + r * 16 + r4;
      int ccol = n0 + wc * 64 + c * 16 + (lane & 15);
      #pragma unroll
      for (int i = 0; i < 4; i++)
        C[(size_t)(crow + i) * N + ccol] = acc[r][c][i];
    }
}

// ---------------- launch ----------------
extern "C" void kernel_launch(void* const* d_in, const int* in_sizes, int n_in,
                              void* d_out, int out_size, void* d_ws, size_t ws_size,
                              hipStream_t stream) {
  const float* x    = (const float*)d_in[0];
  const float* Wq   = (const float*)d_in[1];
  const float* Wk   = (const float*)d_in[2];
  const float* Wg1  = (const float*)d_in[3];
  const float* Wg2  = (const float*)d_in[4];
  const float* Wv   = (const float*)d_in[5];
  const float* Wgp  = (const float*)d_in[6];
  const float* bgp  = (const float*)d_in[7];
  const float* Wout = (const float*)d_in[8];
  float* out = (float*)d_out;

  char* ws = (char*)d_ws;
  float*  Tt     = (float*)(ws + 0);                 // 8388608
  ushort* Stb    = (ushort*)(ws + 8388608);          // 4194304
  float*  gamma  = (float*)(ws + 12582912);          // 65536
  ushort* Qb     = (ushort*)(ws + 12718080);         // 2097152
  ushort* Kb     = (ushort*)(ws + 14815232);         // 2097152
  ushort* Ktb    = (ushort*)(ws + 16912384);         // 2097152
  ushort* Vtb    = (ushort*)(ws + 19009536);         // 4194304
  ushort* xb     = (ushort*)(ws + 23203840);         // 4194304
  ushort* WcatT  = (ushort*)(ws + 27398144);         // 6291456
  ushort* WoutT  = (ushort*)(ws + 33689600);         // 2097152
  ushort* gout   = (ushort*)(ws + 35786752);         // 4194304
  ushort* gsilu  = (ushort*)(ws + 39981056);         // 4194304
  // total 44175360 bytes

  // conversions + gate (fused)
  prep_all_kernel<<<6144, 256, 0, stream>>>(x, Wq, Wk, Wv, Wgp, Wout, Wg1, Wg2,
                                            WcatT, WoutT, gamma, xb);

  // projections with fused prep epilogue + inline prefix (dbuf pipeline + XCD swizzle)
  gemm_proj_kernel<<<dim3(32, 24), 256, 0, stream>>>(xb, WcatT, gamma, bgp,
                                                     Qb, Kb, Ktb, Vtb, gsilu);

  // chunked scan (MFMA) — three kernels; kernel boundaries handle XCD coherence
  chunk_T_kernel<<<dim3(16, 16), 512, 0, stream>>>(Ktb, Vtb, Tt);
  state_kernel<<<dim3(16, 16), 256, 0, stream>>>(Tt, gamma, Stb);
  out_chunk_kernel<<<dim3(16, 16), 512, 0, stream>>>(gamma, Qb, Kb, Stb, Vtb, gsilu, gout);

  // output projection (dbuf pipeline + XCD swizzle)
  gemm_out_kernel<<<dim3(32, 8), 256, 0, stream>>>(gout, WoutT, out);
}

// Round 17
// 82.103 us; speedup vs baseline: 1.0232x; 1.0232x over previous
//
#include <hip/hip_runtime.h>

typedef __bf16 bf16x8 __attribute__((ext_vector_type(8)));
typedef float floatx4 __attribute__((ext_vector_type(4)));

__device__ __forceinline__ ushort f2bf(float f) {
  union { float f; unsigned u; } a; a.f = f;
  unsigned u = a.u;
  unsigned r = (u + 0x7FFFu + ((u >> 16) & 1u)) >> 16;
  return (ushort)r;
}
__device__ __forceinline__ float bf2f(ushort u) {
  union { unsigned u; float f; } a; a.u = ((unsigned)u) << 16;
  return a.f;
}

// async global->LDS, 16B per lane; lds base must be wave-uniform
__device__ __forceinline__ void gl_lds16(const ushort* g, ushort* l) {
  __builtin_amdgcn_global_load_lds((const __attribute__((address_space(1))) void*)g,
                                   (__attribute__((address_space(3))) void*)l, 16, 0, 0);
}

// within-chunk prefix product (sequential scan, 64 lanes)
__device__ __forceinline__ float chunk_scan(float g) {
  int lane = threadIdx.x & 63;
  #pragma unroll
  for (int m = 1; m < 64; m <<= 1) {
    float o = __shfl_up(g, m);
    if (lane >= m) g *= o;
  }
  return g;
}

// swizzled index helpers
#define SWZH(row, col, stride) ((((row) * (stride)) + (col)) ^ (((row) & 7) << 3))       // ushort tiles
#define SWZC(row, col) ((((row) * 128) + (col)) ^ ((((row) >> 3) & 7) << 2))             // f32 C-tile

// LESSONS LOG (final):
// R7/R8: grid-barrier fusion of scan phases = +110us. Keep separate kernels.
// R11:   8-wave 64x128 GEMM = +6us vs 4-wave 2x4-acc.
// R13:   BK=128 = +16us (16-way LDS bank conflicts at 256B row stride).
// R15:   depth-1 dbuf pipeline (stage-next-before-compute) = -3.3us. KEEP.
// R16:   T1 XCD swizzle = +1.8us: operands are L3-resident (<=6MB), so no
//        HBM refetch to save; matches guide m160 "costs ~2% when L3-fit".
//        REVERTED. R15 config = converged optimum of this decomposition.

// ---------------- fused: weight conversions (blocks 0..4095) + gate (4096..6143) ----------------
__global__ __launch_bounds__(256) void prep_all_kernel(
    const float* __restrict__ x,
    const float* __restrict__ Wq, const float* __restrict__ Wk,
    const float* __restrict__ Wv, const float* __restrict__ Wgp,
    const float* __restrict__ Wout,
    const float* __restrict__ Wg1, const float* __restrict__ Wg2,
    ushort* __restrict__ WcatT, ushort* __restrict__ WoutT,
    float* __restrict__ gamma, ushort* __restrict__ xb) {
  __shared__ __align__(16) float smem[1344];
  int bid = blockIdx.x;
  int tid = threadIdx.x;

  if (bid < 4096) {
    int nv = (bid & 127) * 32, k0 = (bid >> 7) * 32;
    const float* W; ushort* dst; int N, ncol, nrow; float scale = 1.f;
    if (nv < 512)       { W = Wq;   N = 512;  ncol = nv;         nrow = nv;        dst = WcatT; }
    else if (nv < 1024) { W = Wk;   N = 512;  ncol = nv - 512;   nrow = nv;        dst = WcatT; scale = 0.125f; }
    else if (nv < 2048) { W = Wv;   N = 1024; ncol = nv - 1024;  nrow = nv;        dst = WcatT; }
    else if (nv < 3072) { W = Wgp;  N = 1024; ncol = nv - 2048;  nrow = nv;        dst = WcatT; }
    else                { W = Wout; N = 1024; ncol = nv - 3072;  nrow = nv - 3072; dst = WoutT; }
    float* tile = smem;  // [32][33]
    int xi = tid & 31, yi = tid >> 5;
    #pragma unroll
    for (int i = 0; i < 32; i += 8)
      tile[(yi + i) * 33 + xi] = W[(size_t)(k0 + yi + i) * N + ncol + xi];
    __syncthreads();
    #pragma unroll
    for (int i = 0; i < 32; i += 8)
      dst[(size_t)(nrow + yi + i) * 1024 + k0 + xi] = f2bf(tile[xi * 33 + yi + i] * scale);
    return;
  }

  int rowi = bid - 4096;          // b*1024 + l
  int b = rowi >> 10, l = rowi & 1023;
  float* xrow = smem;             // 1024
  float* part = smem + 1024;      // [16][17]
  float* tsh  = smem + 1296;      // 16

  {
    float4 v = *(const float4*)(x + (size_t)rowi * 1024 + tid * 4);
    ushort4 o;
    o.x = f2bf(v.x); o.y = f2bf(v.y); o.z = f2bf(v.z); o.w = f2bf(v.w);
    *(ushort4*)(xb + (size_t)rowi * 1024 + tid * 4) = o;
    *(float4*)&xrow[tid * 4] = v;
  }
  __syncthreads();

  {
    int j = tid & 15, slice = tid >> 4;
    const float* xr = xrow + slice * 64;
    float p = 0.f;
    #pragma unroll 4
    for (int kk = 0; kk < 64; kk++)
      p += xr[kk] * Wg1[(size_t)(slice * 64 + kk) * 16 + j];
    part[slice * 17 + j] = p;
  }
  __syncthreads();
  if (tid < 16) {
    float s = 0.f;
    #pragma unroll
    for (int i = 0; i < 16; i++) s += part[i * 17 + tid];
    tsh[tid] = s;
  }
  __syncthreads();

  float ls0, ls1;
  {
    int n = tid;
    float kg = 0.f;
    #pragma unroll
    for (int j = 0; j < 16; j++) kg += tsh[j] * Wg2[j * 512 + n];
    ls0 = (kg >= 0.f) ? -log1pf(expf(-kg)) : (kg - log1pf(expf(kg)));
  }
  {
    int n = tid + 256;
    float kg = 0.f;
    #pragma unroll
    for (int j = 0; j < 16; j++) kg += tsh[j] * Wg2[j * 512 + n];
    ls1 = (kg >= 0.f) ? -log1pf(expf(-kg)) : (kg - log1pf(expf(kg)));
  }
  #pragma unroll
  for (int m = 32; m >= 1; m >>= 1) {
    ls0 += __shfl_xor(ls0, m);
    ls1 += __shfl_xor(ls1, m);
  }
  if ((tid & 63) == 0) {
    int w = tid >> 6;
    gamma[(size_t)(b * 8 + w) * 1024 + l]       = expf(ls0 * (1.f / 1024.f)) + 1e-6f;
    gamma[(size_t)(b * 8 + w + 4) * 1024 + l]   = expf(ls1 * (1.f / 1024.f)) + 1e-6f;
  }
}

// ---------------- projection GEMM, 64x128 tile, 4 waves, BK=64, dbuf pipeline ----------------
__global__ __launch_bounds__(256) void gemm_proj_kernel(
    const ushort* __restrict__ A, const ushort* __restrict__ BT,
    const float* __restrict__ gamma, const float* __restrict__ bgp,
    ushort* __restrict__ Qb, ushort* __restrict__ Kb,
    ushort* __restrict__ Ktb, ushort* __restrict__ Vtb,
    ushort* __restrict__ gsilu) {
  const int K = 1024;
  // 2 x (A 8KB + B 16KB) staging dbuf = 48KB; epilogue Cs (32KB) overlays [0,32KB)
  __shared__ __align__(16) char ldsraw[49152];
  float* Cs = (float*)ldsraw;
  __shared__ float ssh[2][64];
  __shared__ float bsh[128];

  int tid = threadIdx.x;
  int lane = tid & 63, wid = tid >> 6;
  int wr = wid >> 1, wc = wid & 1;
  int m0 = blockIdx.x * 64, n0 = blockIdx.y * 128;
  int by = blockIdx.y;
  int rtype = (by < 4) ? 0 : (by < 8) ? 1 : (by < 16) ? 2 : 3;  // Q,K,V,G
  int b = m0 >> 10, lbase = m0 & 1023;

  // inline prefix-product: waves 0,1 handle the 2 heads
  if (rtype <= 1 && wid < 2) {
    int h = ((n0 - (rtype << 9)) >> 6) + wid;
    int bh = b * 8 + h;
    float a = chunk_scan(gamma[(size_t)bh * 1024 + lbase + lane]);
    float Ac = __shfl(a, 63);
    ssh[wid][lane] = (rtype == 0) ? a : (Ac / a);
  } else if (rtype == 3) {
    if (tid < 128) bsh[tid] = bgp[n0 - 2048 + tid];
  }

  floatx4 acc[2][4];
  #pragma unroll
  for (int r = 0; r < 2; r++)
    #pragma unroll
    for (int c = 0; c < 4; c++)
      acc[r][c] = (floatx4){0.f, 0.f, 0.f, 0.f};

  int srA = wid * 16 + (lane >> 3);
  int srB = wid * 32 + (lane >> 3);
  int sc = (lane & 7) * 8;
  const ushort* ag = A + (size_t)(m0 + srA) * K + sc;
  const ushort* bg = BT + (size_t)(n0 + srB) * K + sc;
  int aoff = (wid * 16) * 64;   // element offset within A region (wave-uniform)
  int boff = (wid * 32) * 64;
  int row = lane & 15, kseg = (lane >> 4) << 3;

  // prologue: stage k0=0 into buffer 0
  {
    ushort* asb = (ushort*)ldsraw + aoff;
    ushort* bsb = (ushort*)(ldsraw + 8192) + boff;
    #pragma unroll
    for (int i = 0; i < 2; i++)
      gl_lds16(ag + (size_t)(i * 8) * K, asb + i * 8 * 64);
    #pragma unroll
    for (int i = 0; i < 4; i++)
      gl_lds16(bg + (size_t)(i * 8) * K, bsb + i * 8 * 64);
  }
  __syncthreads();   // buffer 0 ready

  for (int t = 0; t < 16; t++) {
    int p = t & 1;
    if (t < 15) {    // issue next-tile stage BEFORE compute — latency hides under MFMA
      char* nb = ldsraw + (p ^ 1) * 24576;
      ushort* asb = (ushort*)nb + aoff;
      ushort* bsb = (ushort*)(nb + 8192) + boff;
      int k0 = (t + 1) * 64;
      #pragma unroll
      for (int i = 0; i < 2; i++)
        gl_lds16(ag + (size_t)(i * 8) * K + k0, asb + i * 8 * 64);
      #pragma unroll
      for (int i = 0; i < 4; i++)
        gl_lds16(bg + (size_t)(i * 8) * K + k0, bsb + i * 8 * 64);
    }
    const ushort* As_ = (const ushort*)(ldsraw + p * 24576);
    const ushort* Bs_ = (const ushort*)(ldsraw + p * 24576 + 8192);
    #pragma unroll
    for (int kk = 0; kk < 64; kk += 32) {
      bf16x8 av[2], bv[4];
      #pragma unroll
      for (int r = 0; r < 2; r++)
        av[r] = *(const bf16x8*)&As_[(wr * 32 + r * 16 + row) * 64 + kk + kseg];
      #pragma unroll
      for (int c = 0; c < 4; c++)
        bv[c] = *(const bf16x8*)&Bs_[(wc * 64 + c * 16 + row) * 64 + kk + kseg];
      #pragma unroll
      for (int r = 0; r < 2; r++)
        #pragma unroll
        for (int c = 0; c < 4; c++)
          acc[r][c] = __builtin_amdgcn_mfma_f32_16x16x32_bf16(av[r], bv[c], acc[r][c], 0, 0, 0);
    }
    __syncthreads();  // drains this iteration's stage (hidden under compute) + WAR barrier
  }

  // epilogue: acc -> swizzled f32 LDS tile
  #pragma unroll
  for (int r = 0; r < 2; r++) {
    int crow = wr * 32 + r * 16 + ((lane >> 4) << 2);
    #pragma unroll
    for (int c = 0; c < 4; c++) {
      int ccol = wc * 64 + c * 16 + (lane & 15);
      #pragma unroll
      for (int i = 0; i < 4; i++)
        Cs[SWZC(crow + i, ccol)] = acc[r][c][i];
    }
  }
  __syncthreads();

  if (rtype == 0) {
    #pragma unroll
    for (int it = 0; it < 4; it++) {
      int u = tid + it * 256;
      int rw = u >> 4, col8 = (u & 15) * 8;
      int hh = col8 >> 6, d = col8 & 63;
      float a = ssh[hh][rw];
      float4 v0 = *(const float4*)&Cs[SWZC(rw, col8)];
      float4 v1 = *(const float4*)&Cs[SWZC(rw, col8 + 4)];
      ushort o[8];
      o[0]=f2bf(v0.x*a); o[1]=f2bf(v0.y*a); o[2]=f2bf(v0.z*a); o[3]=f2bf(v0.w*a);
      o[4]=f2bf(v1.x*a); o[5]=f2bf(v1.y*a); o[6]=f2bf(v1.z*a); o[7]=f2bf(v1.w*a);
      int bh = b * 8 + (n0 >> 6) + hh;
      *(uint4*)(Qb + ((size_t)bh * 1024 + lbase + rw) * 64 + d) = *(uint4*)&o[0];
    }
  } else if (rtype == 1) {
    #pragma unroll
    for (int it = 0; it < 4; it++) {
      int u = tid + it * 256;
      int rw = u >> 4, col8 = (u & 15) * 8;
      int hh = col8 >> 6, d = col8 & 63;
      float4 v0 = *(const float4*)&Cs[SWZC(rw, col8)];
      float4 v1 = *(const float4*)&Cs[SWZC(rw, col8 + 4)];
      ushort o[8];
      o[0]=f2bf(v0.x); o[1]=f2bf(v0.y); o[2]=f2bf(v0.z); o[3]=f2bf(v0.w);
      o[4]=f2bf(v1.x); o[5]=f2bf(v1.y); o[6]=f2bf(v1.z); o[7]=f2bf(v1.w);
      int bh = b * 8 + ((n0 - 512) >> 6) + hh;
      *(uint4*)(Kb + ((size_t)bh * 1024 + lbase + rw) * 64 + d) = *(uint4*)&o[0];
    }
    #pragma unroll
    for (int it = 0; it < 4; it++) {
      int u = tid + it * 256;
      int l0 = (u & 7) * 8, dd = (u >> 3) & 63, hh = u >> 9;
      ushort o[8];
      #pragma unroll
      for (int j = 0; j < 8; j++)
        o[j] = f2bf(Cs[SWZC(l0 + j, hh * 64 + dd)] * ssh[hh][l0 + j]);
      int bh = b * 8 + ((n0 - 512) >> 6) + hh;
      *(uint4*)(Ktb + ((size_t)(bh * 64 + dd)) * 1024 + lbase + l0) = *(uint4*)&o[0];
    }
  } else if (rtype == 2) {
    #pragma unroll
    for (int it = 0; it < 4; it++) {
      int u = tid + it * 256;
      int l0 = (u & 7) * 8, e = u >> 3;
      ushort o[8];
      #pragma unroll
      for (int j = 0; j < 8; j++)
        o[j] = f2bf(Cs[SWZC(l0 + j, e)]);
      int bh = b * 8 + ((n0 - 1024) >> 7);
      *(uint4*)(Vtb + ((size_t)(bh * 128 + e)) * 1024 + lbase + l0) = *(uint4*)&o[0];
    }
  } else {
    #pragma unroll
    for (int it = 0; it < 4; it++) {
      int u = tid + it * 256;
      int rw = u >> 4, col8 = (u & 15) * 8;
      float4 v0 = *(const float4*)&Cs[SWZC(rw, col8)];
      float4 v1 = *(const float4*)&Cs[SWZC(rw, col8 + 4)];
      float vv[8] = {v0.x, v0.y, v0.z, v0.w, v1.x, v1.y, v1.z, v1.w};
      ushort o[8];
      #pragma unroll
      for (int j = 0; j < 8; j++) {
        float z = vv[j] + bsh[col8 + j];
        o[j] = f2bf(z / (1.f + expf(-z)));
      }
      *(uint4*)(gsilu + (size_t)(m0 + rw) * 1024 + (n0 - 2048) + col8) = *(uint4*)&o[0];
    }
  }
}

// ---------------- per-chunk Tt[e][d] = sum_s V[s][e] * w_s k[s][d]  (MFMA, 8 waves) ----------------
__global__ __launch_bounds__(512) void chunk_T_kernel(const ushort* __restrict__ Ktb,
                                                      const ushort* __restrict__ Vtb,
                                                      float* __restrict__ Tt) {
  int c = blockIdx.x, bh = blockIdx.y;
  int tid = threadIdx.x;
  int lane = tid & 63, wid = tid >> 6;      // 0..7
  int wq = wid & 3, eh = wid >> 2;
  int col_l = lane & 15, kseg8 = (lane >> 4) * 8;
  int d0w = wq * 16;

  __shared__ __align__(16) ushort Kt[64 * 64];
  __shared__ __align__(16) ushort Vs[128 * 64];

  {
    int row = tid >> 3, col8 = tid & 7;
    *(uint4*)&Kt[SWZH(row, col8 * 8, 64)] =
        *(const uint4*)(Ktb + ((size_t)(bh * 64 + row)) * 1024 + c * 64 + col8 * 8);
  }
  #pragma unroll
  for (int i = 0; i < 2; i++) {
    int u = tid + i * 512;
    int row = u >> 3, col8 = u & 7;
    *(uint4*)&Vs[SWZH(row, col8 * 8, 64)] =
        *(const uint4*)(Vtb + ((size_t)(bh * 128 + row)) * 1024 + c * 64 + col8 * 8);
  }
  __syncthreads();

  floatx4 acc[4];
  #pragma unroll
  for (int i = 0; i < 4; i++) acc[i] = (floatx4){0.f, 0.f, 0.f, 0.f};

  #pragma unroll
  for (int kk = 0; kk < 64; kk += 32) {
    bf16x8 kb = *(const bf16x8*)&Kt[SWZH(d0w + col_l, kk + kseg8, 64)];
    #pragma unroll
    for (int j = 0; j < 4; j++) {
      bf16x8 vb = *(const bf16x8*)&Vs[SWZH((eh * 4 + j) * 16 + col_l, kk + kseg8, 64)];
      acc[j] = __builtin_amdgcn_mfma_f32_16x16x32_bf16(vb, kb, acc[j], 0, 0, 0);
    }
  }

  float* To = Tt + (size_t)(bh * 16 + c) * 8192;
  #pragma unroll
  for (int j = 0; j < 4; j++) {
    #pragma unroll
    for (int r = 0; r < 4; r++) {
      int e = (eh * 4 + j) * 16 + (lane >> 4) * 4 + r;
      To[(size_t)e * 64 + d0w + col_l] = acc[j][r];
    }
  }
}

// ---------------- inter-chunk state recurrence (e-sliced, inline Atot, prefetched) ----------------
__global__ __launch_bounds__(256) void state_kernel(const float* __restrict__ Tt,
                                                    const float* __restrict__ gamma,
                                                    ushort* __restrict__ Stb) {
  int es = blockIdx.x, bh = blockIdx.y;
  int tid = threadIdx.x;
  int lane = tid & 63, wid = tid >> 6;
  __shared__ float Atot_sh[16];

  #pragma unroll
  for (int j = 0; j < 4; j++) {
    int cc = wid * 4 + j;
    float a = chunk_scan(gamma[(size_t)bh * 1024 + cc * 64 + lane]);
    if (lane == 63) Atot_sh[cc] = a;
  }
  __syncthreads();

  size_t off = (size_t)es * 512 + tid * 2;
  float2 t[16];
  #pragma unroll
  for (int c = 0; c < 16; c++)
    t[c] = *(const float2*)(Tt + (size_t)(bh * 16 + c) * 8192 + off);
  float2 S = {0.f, 0.f};
  #pragma unroll
  for (int c = 0; c < 16; c++) {
    ushort2 o; o.x = f2bf(S.x); o.y = f2bf(S.y);
    *(ushort2*)(Stb + (size_t)(bh * 16 + c) * 8192 + off) = o;
    float A = Atot_sh[c];
    S.x = A * S.x + t[c].x;
    S.y = A * S.y + t[c].y;
  }
}

// ---------------- per-chunk output (MFMA, 8 waves) + LN + gate mult -> bf16 ----------------
__global__ __launch_bounds__(512) void out_chunk_kernel(const float* __restrict__ gamma,
                                                        const ushort* __restrict__ Qb,
                                                        const ushort* __restrict__ Kb,
                                                        const ushort* __restrict__ Stb,
                                                        const ushort* __restrict__ Vtb,
                                                        const ushort* __restrict__ gsilu,
                                                        ushort* __restrict__ gout) {
  int c = blockIdx.x, bh = blockIdx.y;
  int b = bh >> 3, h = bh & 7;
  int tid = threadIdx.x;
  int lane = tid & 63, wid = tid >> 6;      // 0..7
  int wq = wid & 3, eh = wid >> 2;
  int col_l = lane & 15, kseg8 = (lane >> 4) * 8;
  int t0w = wq * 16;

  __shared__ __align__(16) ushort Qs[64 * 64];
  __shared__ __align__(16) ushort Ks[64 * 64];
  __shared__ __align__(16) ushort Ss[128 * 64];
  __shared__ __align__(16) ushort Vs[128 * 64];
  __shared__ __align__(16) ushort Ps[64 * 64];
  __shared__ __align__(16) ushort Gz[64 * 128];
  __shared__ float inva_sh[64];
  __shared__ float2 red[2][4][16];

  // inline 1/prefix
  if (wid == 0) {
    float a = chunk_scan(gamma[(size_t)bh * 1024 + c * 64 + lane]);
    inva_sh[lane] = 1.f / a;
  }

  {
    int row = tid >> 3, col8 = tid & 7;
    *(uint4*)&Qs[SWZH(row, col8 * 8, 64)] =
        *(const uint4*)(Qb + ((size_t)(bh * 1024 + c * 64 + row)) * 64 + col8 * 8);
    *(uint4*)&Ks[SWZH(row, col8 * 8, 64)] =
        *(const uint4*)(Kb + ((size_t)(bh * 1024 + c * 64 + row)) * 64 + col8 * 8);
  }
  #pragma unroll
  for (int i = 0; i < 2; i++) {
    int u = tid + i * 512;
    int row = u >> 3, col8 = u & 7;
    *(uint4*)&Ss[SWZH(row, col8 * 8, 64)] =
        *(const uint4*)(Stb + (size_t)(bh * 16 + c) * 8192 + (size_t)row * 64 + col8 * 8);
    *(uint4*)&Vs[SWZH(row, col8 * 8, 64)] =
        *(const uint4*)(Vtb + ((size_t)(bh * 128 + row)) * 1024 + c * 64 + col8 * 8);
  }
  #pragma unroll
  for (int i = 0; i < 2; i++) {
    int u = tid + i * 512;
    int row = u >> 4, ch = u & 15;
    *(uint4*)&Gz[SWZH(row, ch * 8, 128)] =
        *(const uint4*)(gsilu + ((size_t)(b * 1024 + c * 64 + row)) * 1024 + h * 128 + ch * 8);
  }
  __syncthreads();

  floatx4 pacc[2];
  floatx4 acc[4];
  #pragma unroll
  for (int i = 0; i < 2; i++) pacc[i] = (floatx4){0.f, 0.f, 0.f, 0.f};
  #pragma unroll
  for (int i = 0; i < 4; i++) acc[i] = (floatx4){0.f, 0.f, 0.f, 0.f};

  #pragma unroll
  for (int kk = 0; kk < 64; kk += 32) {
    bf16x8 qb = *(const bf16x8*)&Qs[SWZH(t0w + col_l, kk + kseg8, 64)];
    #pragma unroll
    for (int j = 0; j < 2; j++) {
      int fs = eh * 2 + j;
      bf16x8 kb = *(const bf16x8*)&Ks[SWZH(fs * 16 + col_l, kk + kseg8, 64)];
      pacc[j] = __builtin_amdgcn_mfma_f32_16x16x32_bf16(kb, qb, pacc[j], 0, 0, 0);
    }
    #pragma unroll
    for (int j = 0; j < 4; j++) {
      int fe = eh * 4 + j;
      bf16x8 sb = *(const bf16x8*)&Ss[SWZH(fe * 16 + col_l, kk + kseg8, 64)];
      acc[j] = __builtin_amdgcn_mfma_f32_16x16x32_bf16(sb, qb, acc[j], 0, 0, 0);
    }
  }

  int tl = t0w + col_l;
  #pragma unroll
  for (int j = 0; j < 2; j++) {
    int fs = eh * 2 + j;
    ushort o[4];
    #pragma unroll
    for (int r = 0; r < 4; r++) {
      int s = fs * 16 + (lane >> 4) * 4 + r;
      float pv = (s <= tl) ? pacc[j][r] * inva_sh[s] : 0.f;
      o[r] = f2bf(pv);
    }
    int s0 = fs * 16 + (lane >> 4) * 4;
    *(ushort4*)&Ps[SWZH(tl, s0, 64)] = *(ushort4*)&o[0];
  }
  __syncthreads();

  #pragma unroll
  for (int kk = 0; kk < 64; kk += 32) {
    bf16x8 pb = *(const bf16x8*)&Ps[SWZH(t0w + col_l, kk + kseg8, 64)];
    #pragma unroll
    for (int j = 0; j < 4; j++) {
      int fe = eh * 4 + j;
      bf16x8 vb = *(const bf16x8*)&Vs[SWZH(fe * 16 + col_l, kk + kseg8, 64)];
      acc[j] = __builtin_amdgcn_mfma_f32_16x16x32_bf16(vb, pb, acc[j], 0, 0, 0);
    }
  }
  __syncthreads();

  float s1 = 0.f, s2 = 0.f;
  #pragma unroll
  for (int j = 0; j < 4; j++)
    #pragma unroll
    for (int r = 0; r < 4; r++) {
      float v = acc[j][r];
      s1 += v; s2 += v * v;
    }
  s1 += __shfl_xor(s1, 16); s2 += __shfl_xor(s2, 16);
  s1 += __shfl_xor(s1, 32); s2 += __shfl_xor(s2, 32);
  if (lane < 16) red[eh][wq][lane] = make_float2(s1, s2);
  __syncthreads();
  float2 oth = red[1 - eh][wq][col_l];
  float S1 = s1 + oth.x, S2 = s2 + oth.y;
  float mu = S1 * (1.f / 128.f);
  float var = S2 * (1.f / 128.f) - mu * mu;
  float rs = rsqrtf(var + 1e-5f);

  ushort* Gs = Vs;  // reuse (Vs reads done, synced above)
  #pragma unroll
  for (int j = 0; j < 4; j++)
    #pragma unroll
    for (int r = 0; r < 4; r++) {
      int e = (eh * 4 + j) * 16 + (lane >> 4) * 4 + r;
      float y = (acc[j][r] - mu) * rs;
      float g = bf2f(Gz[SWZH(tl, e, 128)]);
      Gs[SWZH(tl, e, 128)] = f2bf(y * g);
    }
  __syncthreads();

  #pragma unroll
  for (int i = 0; i < 2; i++) {
    int u = tid + i * 512;
    int row = u >> 4, ch = u & 15;
    *(uint4*)(gout + ((size_t)(b * 1024 + c * 64 + row)) * 1024 + h * 128 + ch * 8) =
        *(uint4*)&Gs[SWZH(row, ch * 8, 128)];
  }
}

// ---------------- output GEMM: 64x128 tile, 4 waves, BK=64, dbuf pipeline ----------------
__global__ __launch_bounds__(256) void gemm_out_kernel(const ushort* __restrict__ A,
                                                       const ushort* __restrict__ BT,
                                                       float* __restrict__ C) {
  const int K = 1024, N = 1024;
  __shared__ __align__(16) char ldsraw[49152];   // 2 x (A 8KB + B 16KB)
  int tid = threadIdx.x;
  int lane = tid & 63, wid = tid >> 6;
  int wr = wid >> 1, wc = wid & 1;
  int m0 = blockIdx.x * 64, n0 = blockIdx.y * 128;
  int row = lane & 15, kseg = (lane >> 4) << 3;

  floatx4 acc[2][4];
  #pragma unroll
  for (int r = 0; r < 2; r++)
    #pragma unroll
    for (int c = 0; c < 4; c++)
      acc[r][c] = (floatx4){0.f, 0.f, 0.f, 0.f};

  int srowA = wid * 16 + (lane >> 3);
  int srowB = wid * 32 + (lane >> 3);
  int scol = (lane & 7) * 8;
  const ushort* ag = A + (size_t)(m0 + srowA) * K + scol;
  const ushort* bg = BT + (size_t)(n0 + srowB) * K + scol;
  int aoff = (wid * 16) * 64;
  int boff = (wid * 32) * 64;

  {
    ushort* asb = (ushort*)ldsraw + aoff;
    ushort* bsb = (ushort*)(ldsraw + 8192) + boff;
    #pragma unroll
    for (int i = 0; i < 2; i++)
      gl_lds16(ag + (size_t)(i * 8) * K, asb + i * 8 * 64);
    #pragma unroll
    for (int i = 0; i < 4; i++)
      gl_lds16(bg + (size_t)(i * 8) * K, bsb + i * 8 * 64);
  }
  __syncthreads();

  for (int t = 0; t < 16; t++) {
    int p = t & 1;
    if (t < 15) {
      char* nb = ldsraw + (p ^ 1) * 24576;
      ushort* asb = (ushort*)nb + aoff;
      ushort* bsb = (ushort*)(nb + 8192) + boff;
      int k0 = (t + 1) * 64;
      #pragma unroll
      for (int i = 0; i < 2; i++)
        gl_lds16(ag + (size_t)(i * 8) * K + k0, asb + i * 8 * 64);
      #pragma unroll
      for (int i = 0; i < 4; i++)
        gl_lds16(bg + (size_t)(i * 8) * K + k0, bsb + i * 8 * 64);
    }
    const ushort* As_ = (const ushort*)(ldsraw + p * 24576);
    const ushort* Bs_ = (const ushort*)(ldsraw + p * 24576 + 8192);
    #pragma unroll
    for (int kk = 0; kk < 64; kk += 32) {
      bf16x8 av[2], bv[4];
      #pragma unroll
      for (int r = 0; r < 2; r++)
        av[r] = *(const bf16x8*)&As_[(wr * 32 + r * 16 + row) * 64 + kk + kseg];
      #pragma unroll
      for (int c = 0; c < 4; c++)
        bv[c] = *(const bf16x8*)&Bs_[(wc * 64 + c * 16 + row) * 64 + kk + kseg];
      #pragma unroll
      for (int r = 0; r < 2; r++)
        #pragma unroll
        for (int c = 0; c < 4; c++)
          acc[r][c] = __builtin_amdgcn_mfma_f32_16x16x32_bf16(av[r], bv[c], acc[r][c], 0, 0, 0);
    }
    __syncthreads();
  }

  int r4 = (lane >> 4) << 2;
  #pragma unroll
  for (int r = 0; r < 2; r++)
    #pragma unroll
    for (int c = 0; c < 4; c++) {
      int crow = m0 + wr * 32 + r * 16 + r4;
      int ccol = n0 + wc * 64 + c * 16 + (lane & 15);
      #pragma unroll
      for (int i = 0; i < 4; i++)
        C[(size_t)(crow + i) * N + ccol] = acc[r][c][i];
    }
}

// ---------------- launch ----------------
extern "C" void kernel_launch(void* const* d_in, const int* in_sizes, int n_in,
                              void* d_out, int out_size, void* d_ws, size_t ws_size,
                              hipStream_t stream) {
  const float* x    = (const float*)d_in[0];
  const float* Wq   = (const float*)d_in[1];
  const float* Wk   = (const float*)d_in[2];
  const float* Wg1  = (const float*)d_in[3];
  const float* Wg2  = (const float*)d_in[4];
  const float* Wv   = (const float*)d_in[5];
  const float* Wgp  = (const float*)d_in[6];
  const float* bgp  = (const float*)d_in[7];
  const float* Wout = (const float*)d_in[8];
  float* out = (float*)d_out;

  char* ws = (char*)d_ws;
  float*  Tt     = (float*)(ws + 0);                 // 8388608
  ushort* Stb    = (ushort*)(ws + 8388608);          // 4194304
  float*  gamma  = (float*)(ws + 12582912);          // 65536
  ushort* Qb     = (ushort*)(ws + 12718080);         // 2097152
  ushort* Kb     = (ushort*)(ws + 14815232);         // 2097152
  ushort* Ktb    = (ushort*)(ws + 16912384);         // 2097152
  ushort* Vtb    = (ushort*)(ws + 19009536);         // 4194304
  ushort* xb     = (ushort*)(ws + 23203840);         // 4194304
  ushort* WcatT  = (ushort*)(ws + 27398144);         // 6291456
  ushort* WoutT  = (ushort*)(ws + 33689600);         // 2097152
  ushort* gout   = (ushort*)(ws + 35786752);         // 4194304
  ushort* gsilu  = (ushort*)(ws + 39981056);         // 4194304
  // total 44175360 bytes

  // conversions + gate (fused)
  prep_all_kernel<<<6144, 256, 0, stream>>>(x, Wq, Wk, Wv, Wgp, Wout, Wg1, Wg2,
                                            WcatT, WoutT, gamma, xb);

  // projections with fused prep epilogue + inline prefix (dbuf pipeline)
  gemm_proj_kernel<<<dim3(32, 24), 256, 0, stream>>>(xb, WcatT, gamma, bgp,
                                                     Qb, Kb, Ktb, Vtb, gsilu);

  // chunked scan (MFMA) — three kernels; kernel boundaries handle XCD coherence
  chunk_T_kernel<<<dim3(16, 16), 512, 0, stream>>>(Ktb, Vtb, Tt);
  state_kernel<<<dim3(16, 16), 256, 0, stream>>>(Tt, gamma, Stb);
  out_chunk_kernel<<<dim3(16, 16), 512, 0, stream>>>(gamma, Qb, Kb, Stb, Vtb, gsilu, gout);

  // output projection (dbuf pipeline)
  gemm_out_kernel<<<dim3(32, 8), 256, 0, stream>>>(gout, WoutT, out);
}